// Round 3
// baseline (307.180 us; speedup 1.0000x reference)
//
#include <hip/hip_runtime.h>
#include <stdint.h>

// ClusteringLayer: q = rownorm(1/(1 + ||x||^2 + ||c||^2 - 2 x@c^T))
// N=65536, D=512, K=512.
// v4: fix register-starved memory ILP. v1-v3 all compiled at 64 arch VGPRs
// (launch_bounds(512,4) + 64 AGPR acc == the 128-reg occupancy bucket), so
// loads serialized and every pipe idled (~350 TF equiv). Re-shape: 1024-thr
// blocks, wave tile 64x32 -> acc is 32 AGPR/lane, freeing ~96 VGPRs for
// in-flight loads at unchanged 16-waves/CU occupancy. B read 2-deep-pipelined
// straight from the L2-resident fragment-major image (1x redundancy now).
// Each block does TWO 64-row tiles; tile-1 x-loads fly during tile-0 epilogue.

#define D 512
#define K 512
#define BM 64
#define THREADS 1024
#define ESTRIDE 516      // padded f32 row stride for epilogue transpose slices

typedef __attribute__((ext_vector_type(8))) short short8;   // 8 x bf16
typedef __attribute__((ext_vector_type(4))) float floatx4;  // MFMA acc

#define BARRIER() do {                                      \
    asm volatile("s_waitcnt lgkmcnt(0)" ::: "memory");      \
    __builtin_amdgcn_s_barrier();                           \
    asm volatile("" ::: "memory");                          \
  } while (0)

// fp32 -> bf16 round-to-nearest-even
__device__ __forceinline__ uint16_t f2bf(float f) {
  uint32_t u = __float_as_uint(f);
  u += 0x7FFFu + ((u >> 16) & 1u);
  return (uint16_t)(u >> 16);
}

__device__ __forceinline__ uint4 pack8(float4 v0, float4 v1) {
  uint4 pk;
  pk.x = (uint32_t)f2bf(v0.x) | ((uint32_t)f2bf(v0.y) << 16);
  pk.y = (uint32_t)f2bf(v0.z) | ((uint32_t)f2bf(v0.w) << 16);
  pk.z = (uint32_t)f2bf(v1.x) | ((uint32_t)f2bf(v1.y) << 16);
  pk.w = (uint32_t)f2bf(v1.z) | ((uint32_t)f2bf(v1.w) << 16);
  return pk;
}

__device__ __forceinline__ float sq8(float4 v0, float4 v1) {
  return v0.x*v0.x + v0.y*v0.y + v0.z*v0.z + v0.w*v0.w
       + v1.x*v1.x + v1.y*v1.y + v1.z*v1.z + v1.w*v1.w;
}

// ---------------------------------------------------------------------------
// Prep: centroids fp32 -> bf16 in fragment-major layout (as v3):
//   16B slot = (ks*512 + row)*4 + quad,  ks = 0..15 (k-step of 32)
// A wave's fragment read (fixed ks,ni) is one contiguous, coalesced 1KB.
// Also ||c||^2 per centroid.
// ---------------------------------------------------------------------------
__global__ __launch_bounds__(64)
void prep_kernel(const float* __restrict__ cent, float* __restrict__ csq,
                 uint16_t* __restrict__ bbf) {
  const int row  = blockIdx.x;     // 0..511
  const int lane = threadIdx.x;    // 0..63, 8 floats each
  const float4* src = (const float4*)(cent + (size_t)row * D + lane * 8);
  float4 v0 = src[0];
  float4 v1 = src[1];
  float ss = sq8(v0, v1);
  uint4 pk = pack8(v0, v1);
  const int ks = lane >> 2;        // k-step of 32 (8 floats/lane => lane/4)
  const int qd = lane & 3;         // quad within k-step
  const int slot = (ks * 512 + row) * 4 + qd;
  *(uint4*)(bbf + (size_t)slot * 8) = pk;
  #pragma unroll
  for (int m = 1; m < 64; m <<= 1) ss += __shfl_xor(ss, m);
  if (lane == 0) csq[row] = ss;
}

// ---------------------------------------------------------------------------
// Main fused kernel. 1024 threads = 16 waves; block covers 2 tiles of 64 rows
// x all 512 centroids. Wave w owns cols [32w, 32w+32): 4x2 frags of 16x16x32.
// A tile in LDS uses the v2-proven per-chunk layout (row stride 128B, XOR
// swizzle) -> 0 bank conflicts.
// ---------------------------------------------------------------------------
__global__ __launch_bounds__(THREADS, 4)
void cluster_main(const float* __restrict__ x, const uint16_t* __restrict__ bbf,
                  const float* __restrict__ csq, float* __restrict__ out) {
  __shared__ __align__(16) char smem[BM * D * 2];   // 64KB: A tile / ebuf
  __shared__ float lxsq[BM];
  __shared__ float lrow[BM];
  uint16_t* const lA = (uint16_t*)smem;
  float* const ebuf  = (float*)smem;

  const int tid  = threadIdx.x;
  const int w    = tid >> 6;      // wave 0..15
  const int lane = tid & 63;
  const int p    = lane & 15;     // MFMA row/col-within-16
  const int quad = lane >> 4;     // MFMA quad
  const int ar   = tid >> 4;      // staging row 0..63
  const int ag   = tid & 15;      // staging col-phase 0..15

  // per-lane B base (u16 units) into the fragment-major image
  const uint16_t* const bl = bbf + ((w * 32 + p) * 32 + quad * 8);

  const size_t tbase0 = (size_t)blockIdx.x * (2 * BM);

  // ---- prefetch tile 0's x (8 float4 in flight; we have the VGPRs now) ----
  float4 hv[8];
  {
    const float* xr = x + (tbase0 + ar) * D + ag * 8;
    #pragma unroll
    for (int j = 0; j < 4; ++j) {
      hv[2*j]   = *(const float4*)(xr + j * 128);
      hv[2*j+1] = *(const float4*)(xr + j * 128 + 4);
    }
  }

  #pragma unroll 1
  for (int t = 0; t < 2; ++t) {
    if (t) BARRIER();              // epi(t-1) LDS reads done before overwrite

    // ---- convert + stage A tile (chunk-major, 128B row stride, swizzled):
    //      u16 idx = chunk*4096 + ar*64 + ((g&7)^(ar&7))*8,  chunk = g>>3
    float xacc = 0.f;
    #pragma unroll
    for (int j = 0; j < 4; ++j) {
      xacc += sq8(hv[2*j], hv[2*j+1]);
      const int g = ag + 16 * j;   // col-group 0..63
      *(uint4*)(lA + (g >> 3) * 4096 + ar * 64 + (((g & 7) ^ (ar & 7)) * 8)) =
          pack8(hv[2*j], hv[2*j+1]);
    }
    // ||x||^2: 16 contributing lanes per row are consecutive (same wave)
    xacc += __shfl_xor(xacc, 1);
    xacc += __shfl_xor(xacc, 2);
    xacc += __shfl_xor(xacc, 4);
    xacc += __shfl_xor(xacc, 8);
    if (ag == 0) lxsq[ar] = xacc;
    if (tid < BM) lrow[tid] = 0.f;
    BARRIER();

    floatx4 acc[4][2];
    #pragma unroll
    for (int mi = 0; mi < 4; ++mi)
      #pragma unroll
      for (int ni = 0; ni < 2; ++ni)
        acc[mi][ni] = (floatx4){0.f, 0.f, 0.f, 0.f};

    // ---- barrier-free K loop: 16 k-steps, B 2-deep pipelined from L2 ----
    short8 bE[2], bO[2];
    #pragma unroll
    for (int ni = 0; ni < 2; ++ni)
      bE[ni] = *(const short8*)(bl + ni * 512);

    #pragma unroll
    for (int s8 = 0; s8 < 8; ++s8) {
      const int ks0 = 2 * s8, ks1 = ks0 + 1;

      #pragma unroll
      for (int ni = 0; ni < 2; ++ni)
        bO[ni] = *(const short8*)(bl + ks1 * 16384 + ni * 512);

      #pragma unroll
      for (int mi = 0; mi < 4; ++mi) {
        const int r = mi * 16 + p;
        short8 af = *(const short8*)(
            lA + (ks0 >> 1) * 4096 + r * 64 +
            ((((ks0 & 1) * 4 + quad) ^ (r & 7)) * 8));
        #pragma unroll
        for (int ni = 0; ni < 2; ++ni)
          acc[mi][ni] = __builtin_amdgcn_mfma_f32_16x16x32_bf16(
              af, bE[ni], acc[mi][ni], 0, 0, 0);
      }

      if (s8 < 7) {
        #pragma unroll
        for (int ni = 0; ni < 2; ++ni)
          bE[ni] = *(const short8*)(bl + (ks0 + 2) * 16384 + ni * 512);
      }

      #pragma unroll
      for (int mi = 0; mi < 4; ++mi) {
        const int r = mi * 16 + p;
        short8 af = *(const short8*)(
            lA + (ks1 >> 1) * 4096 + r * 64 +
            ((((ks1 & 1) * 4 + quad) ^ (r & 7)) * 8));
        #pragma unroll
        for (int ni = 0; ni < 2; ++ni)
          acc[mi][ni] = __builtin_amdgcn_mfma_f32_16x16x32_bf16(
              af, bO[ni], acc[mi][ni], 0, 0, 0);
      }
    }

    // ---- issue tile-1 x loads now; they fly during tile-0's epilogue ----
    if (t == 0) {
      const float* xr = x + (tbase0 + BM + ar) * D + ag * 8;
      #pragma unroll
      for (int j = 0; j < 4; ++j) {
        hv[2*j]   = *(const float4*)(xr + j * 128);
        hv[2*j+1] = *(const float4*)(xr + j * 128 + 4);
      }
    }

    // ---- epilogue: q = rcp(1 + xsq + csq - 2*dot); fused row-normalize ----
    float cs[2];
    #pragma unroll
    for (int ni = 0; ni < 2; ++ni)
      cs[ni] = csq[w * 32 + ni * 16 + p];    // tiny, L2-hot

    float rp[4][4];
    #pragma unroll
    for (int mi = 0; mi < 4; ++mi) {
      #pragma unroll
      for (int rr = 0; rr < 4; ++rr) rp[mi][rr] = 0.f;
    }

    #pragma unroll
    for (int mi = 0; mi < 4; ++mi) {
      #pragma unroll
      for (int rr = 0; rr < 4; ++rr) {
        const float xsv = lxsq[mi * 16 + quad * 4 + rr];
        #pragma unroll
        for (int ni = 0; ni < 2; ++ni) {
          const float d = 1.0f + xsv + cs[ni] - 2.0f * acc[mi][ni][rr];
          const float q = __builtin_amdgcn_rcpf(d);  // d ~ 1000, 1ulp ok
          acc[mi][ni][rr] = q;
          rp[mi][rr] += q;
        }
      }
    }

    #pragma unroll
    for (int mi = 0; mi < 4; ++mi)
      #pragma unroll
      for (int rr = 0; rr < 4; ++rr) {
        float v = rp[mi][rr];
        v += __shfl_xor(v, 1);
        v += __shfl_xor(v, 2);
        v += __shfl_xor(v, 4);
        v += __shfl_xor(v, 8);
        if (p == 0) atomicAdd(&lrow[mi * 16 + quad * 4 + rr], v);
      }
    BARRIER();   // lrow complete; all waves' K-loop/lA reads done

    // Transposed store through LDS (reusing the dead A tile): 4 slices of
    // 16 rows (slice s == fragment mi=s); stores are contiguous per wave.
    #pragma unroll
    for (int s = 0; s < 4; ++s) {
      if (s) BARRIER();              // prior slice's reads complete
      float invs[4];
      #pragma unroll
      for (int rr = 0; rr < 4; ++rr)
        invs[rr] = __builtin_amdgcn_rcpf(lrow[s * 16 + quad * 4 + rr]);
      #pragma unroll
      for (int ni = 0; ni < 2; ++ni)
        #pragma unroll
        for (int rr = 0; rr < 4; ++rr)
          ebuf[(quad * 4 + rr) * ESTRIDE + w * 32 + ni * 16 + p] =
              acc[s][ni][rr] * invs[rr];
      BARRIER();
      #pragma unroll
      for (int j = 0; j < 2; ++j) {
        const int idx = j * 1024 + tid;      // 0..2047
        const int r  = idx >> 7;             // 0..15
        const int c4 = idx & 127;            // float4 column
        const float4 v = *(const float4*)&ebuf[r * ESTRIDE + c4 * 4];
        *(float4*)(out + (tbase0 + (size_t)t * BM + s * 16 + r) * K + c4 * 4) = v;
      }
    }
  }
}

extern "C" void kernel_launch(void* const* d_in, const int* in_sizes, int n_in,
                              void* d_out, int out_size, void* d_ws, size_t ws_size,
                              hipStream_t stream) {
  const float* x    = (const float*)d_in[0];
  const float* cent = (const float*)d_in[1];
  float* out = (float*)d_out;

  // ws layout: csq[512] floats (2KB) | bbf bf16 image (512KB). Needs 526KB.
  float*    csq = (float*)d_ws;
  uint16_t* bbf = (uint16_t*)((char*)d_ws + 2048);

  const int N = in_sizes[0] / D;      // 65536
  prep_kernel<<<K, 64, 0, stream>>>(cent, csq, bbf);
  cluster_main<<<N / (2 * BM), THREADS, 0, stream>>>(x, bbf, csq, out);
}

// Round 4
// 293.581 us; speedup vs baseline: 1.0463x; 1.0463x over previous
//
#include <hip/hip_runtime.h>
#include <stdint.h>

// ClusteringLayer: q = rownorm(1/(1 + ||x||^2 + ||c||^2 - 2 x@c^T))
// N=65536, D=512, K=512.
// v5: phase-independence fix. Counters across v1-v4: HBM reads 0.8 TB/s,
// writes 1.5 TB/s, MfmaUtil 13%, VALU 16% -- nothing saturated => latency-
// bound. Root cause: 64-AGPR acc pins every variant to the 128-reg bucket
// (16 waves/CU) arranged as 1-2 SYNCHRONIZED blocks whose read/compute/write
// bursts convoy. Fix: same 16 waves/CU but as FOUR independent 256-thread
// blocks (BM=32), so one block's write burst overlaps another's x reads and
// a third's MFMAs. Plus non-temporal output stores: FETCH(78MB) < x(134MB)
// proves x is partially L3-served and out evicts it; nt stores keep out off
// L2/L3 so x stays L3-resident and B stays L2-hot.

#define D 512
#define K 512
#define BM 32
#define BK 64          // D-chunk per LDS stage
#define NCHUNK (D / BK)
#define THREADS 256

typedef __attribute__((ext_vector_type(8))) short short8;   // 8 x bf16
typedef __attribute__((ext_vector_type(4))) float floatx4;  // MFMA acc

#define BARRIER() do {                                      \
    asm volatile("s_waitcnt lgkmcnt(0)" ::: "memory");      \
    __builtin_amdgcn_s_barrier();                           \
    asm volatile("" ::: "memory");                          \
  } while (0)

// fp32 -> bf16 round-to-nearest-even
__device__ __forceinline__ uint16_t f2bf(float f) {
  uint32_t u = __float_as_uint(f);
  u += 0x7FFFu + ((u >> 16) & 1u);
  return (uint16_t)(u >> 16);
}

__device__ __forceinline__ uint4 pack8(float4 v0, float4 v1) {
  uint4 pk;
  pk.x = (uint32_t)f2bf(v0.x) | ((uint32_t)f2bf(v0.y) << 16);
  pk.y = (uint32_t)f2bf(v0.z) | ((uint32_t)f2bf(v0.w) << 16);
  pk.z = (uint32_t)f2bf(v1.x) | ((uint32_t)f2bf(v1.y) << 16);
  pk.w = (uint32_t)f2bf(v1.z) | ((uint32_t)f2bf(v1.w) << 16);
  return pk;
}

__device__ __forceinline__ float sq8(float4 v0, float4 v1) {
  return v0.x*v0.x + v0.y*v0.y + v0.z*v0.z + v0.w*v0.w
       + v1.x*v1.x + v1.y*v1.y + v1.z*v1.z + v1.w*v1.w;
}

// ---------------------------------------------------------------------------
// Prep (unchanged): centroids fp32 -> bf16 in fragment-major layout:
//   16B slot = (ks*512 + row)*4 + quad,  ks = 0..15 (k-step of 32)
// A wave's fragment read (fixed ks,ni) is one contiguous, coalesced 1KB.
// Also ||c||^2 per centroid.
// ---------------------------------------------------------------------------
__global__ __launch_bounds__(64)
void prep_kernel(const float* __restrict__ cent, float* __restrict__ csq,
                 uint16_t* __restrict__ bbf) {
  const int row  = blockIdx.x;     // 0..511
  const int lane = threadIdx.x;    // 0..63, 8 floats each
  const float4* src = (const float4*)(cent + (size_t)row * D + lane * 8);
  float4 v0 = src[0];
  float4 v1 = src[1];
  float ss = sq8(v0, v1);
  uint4 pk = pack8(v0, v1);
  const int ks = lane >> 2;        // k-step of 32
  const int qd = lane & 3;         // quad within k-step
  const int slot = (ks * 512 + row) * 4 + qd;
  *(uint4*)(bbf + (size_t)slot * 8) = pk;
  #pragma unroll
  for (int m = 1; m < 64; m <<= 1) ss += __shfl_xor(ss, m);
  if (lane == 0) csq[row] = ss;
}

// ---------------------------------------------------------------------------
// Main fused kernel. 256 threads = 4 waves; block = 32 rows x all 512 cols.
// Wave w owns cols [128w, 128w+128): 2x8 frags of 16x16x32 (acc = 64 AGPR).
// A per-chunk double-buffered in LDS (8 KB total); B direct from L2 image in
// ni-halves; x prefetch flies across lgkm-only barriers (FIFO discipline).
// ---------------------------------------------------------------------------
__global__ __launch_bounds__(THREADS, 4)
void cluster_main(const float* __restrict__ x, const uint16_t* __restrict__ bbf,
                  const float* __restrict__ csq, float* __restrict__ out) {
  __shared__ __align__(16) uint16_t lA[2][BM * BK];   // 2 x 4 KB, swizzled
  __shared__ float lxsq[BM];
  __shared__ float lrow[BM];

  const int tid  = threadIdx.x;
  const int w    = tid >> 6;      // wave 0..3
  const int lane = tid & 63;
  const int p    = lane & 15;     // MFMA row/col-within-16
  const int quad = lane >> 4;     // MFMA quad
  const int row0 = blockIdx.x * BM;

  if (tid < BM) lrow[tid] = 0.f;

  // A staging: thread -> (row ar 0..31, 8-col group ag 0..7), chunk-invariant
  const int ar = tid >> 3;
  const int ag = tid & 7;
  const int adst = ar * 64 + ((ag ^ (ar & 7)) * 8);   // u16 offset in a buffer
  const float* xp = x + (size_t)(row0 + ar) * D + ag * 8;
  float xacc = 0.f;

  // per-lane B base (u16) into fragment-major image; strides (u16):
  //   ni: 512, kk (k-step of 32): 16384, chunk: 32768
  const uint16_t* const bl = bbf + (((size_t)(w * 128 + p) * 4 + quad) * 8);

  floatx4 acc[2][8];
  #pragma unroll
  for (int mi = 0; mi < 2; ++mi)
    #pragma unroll
    for (int ni = 0; ni < 8; ++ni)
      acc[mi][ni] = (floatx4){0.f, 0.f, 0.f, 0.f};

  // ---- prologue: stage chunk 0, issue chunk-1 x loads (fly across barrier)
  {
    float4 a0 = *(const float4*)xp;
    float4 a1 = *(const float4*)(xp + 4);
    xp += BK;
    xacc += sq8(a0, a1);
    *(uint4*)&lA[0][adst] = pack8(a0, a1);
  }
  float4 nv0 = *(const float4*)xp;
  float4 nv1 = *(const float4*)(xp + 4);
  xp += BK;
  BARRIER();

  #pragma unroll
  for (int c = 0; c < NCHUNK; ++c) {
    const int cur = c & 1;
    const uint16_t* const bc0 = bl + (size_t)c * 32768;          // kk=0
    const uint16_t* const bc1 = bc0 + 16384;                     // kk=1

    short8 b0[4], b1[4];

    // kk0 ni0-3 loads first; the convert below waits the OLDER x loads,
    // leaving these in flight (FIFO vmcnt).
    #pragma unroll
    for (int ni = 0; ni < 4; ++ni)
      b0[ni] = *(const short8*)(bc0 + ni * 512);

    // stage chunk c+1 into the other buffer
    if (c < NCHUNK - 1) {
      xacc += sq8(nv0, nv1);
      *(uint4*)&lA[cur ^ 1][adst] = pack8(nv0, nv1);
    }

    // kk0 ni4-7, then the x prefetch LAST (newest -> survives all waits)
    #pragma unroll
    for (int ni = 0; ni < 4; ++ni)
      b1[ni] = *(const short8*)(bc0 + 2048 + ni * 512);
    if (c < NCHUNK - 2) {
      nv0 = *(const float4*)xp;
      nv1 = *(const float4*)(xp + 4);
      xp += BK;
    }

    // A fragments for kk0
    short8 af0[2];
    #pragma unroll
    for (int mi = 0; mi < 2; ++mi) {
      const int r = mi * 16 + p;
      af0[mi] = *(const short8*)&lA[cur][r * 64 + ((quad ^ (r & 7)) * 8)];
    }
    // MFMA kk0 ni0-3 (waits b0; b1 + x still flying)
    #pragma unroll
    for (int mi = 0; mi < 2; ++mi)
      #pragma unroll
      for (int ni = 0; ni < 4; ++ni)
        acc[mi][ni] = __builtin_amdgcn_mfma_f32_16x16x32_bf16(
            af0[mi], b0[ni], acc[mi][ni], 0, 0, 0);

    // kk1 ni0-3 into b0 (regs free after consumption)
    #pragma unroll
    for (int ni = 0; ni < 4; ++ni)
      b0[ni] = *(const short8*)(bc1 + ni * 512);

    // MFMA kk0 ni4-7 (waits b1)
    #pragma unroll
    for (int mi = 0; mi < 2; ++mi)
      #pragma unroll
      for (int ni = 0; ni < 4; ++ni)
        acc[mi][ni + 4] = __builtin_amdgcn_mfma_f32_16x16x32_bf16(
            af0[mi], b1[ni], acc[mi][ni + 4], 0, 0, 0);

    // kk1 ni4-7 into b1
    #pragma unroll
    for (int ni = 0; ni < 4; ++ni)
      b1[ni] = *(const short8*)(bc1 + 2048 + ni * 512);

    // A fragments for kk1
    short8 af1[2];
    #pragma unroll
    for (int mi = 0; mi < 2; ++mi) {
      const int r = mi * 16 + p;
      af1[mi] = *(const short8*)&lA[cur][r * 64 + (((4 + quad) ^ (r & 7)) * 8)];
    }
    // MFMA kk1 ni0-3
    #pragma unroll
    for (int mi = 0; mi < 2; ++mi)
      #pragma unroll
      for (int ni = 0; ni < 4; ++ni)
        acc[mi][ni] = __builtin_amdgcn_mfma_f32_16x16x32_bf16(
            af1[mi], b0[ni], acc[mi][ni], 0, 0, 0);
    // MFMA kk1 ni4-7 (only x remains in flight afterwards)
    #pragma unroll
    for (int mi = 0; mi < 2; ++mi)
      #pragma unroll
      for (int ni = 0; ni < 4; ++ni)
        acc[mi][ni + 4] = __builtin_amdgcn_mfma_f32_16x16x32_bf16(
            af1[mi], b1[ni], acc[mi][ni + 4], 0, 0, 0);

    if (c < NCHUNK - 1) BARRIER();   // lgkm-only; x prefetch stays in flight
  }

  // ---- ||x||^2 per row (8 consecutive contributing lanes per row) ----
  xacc += __shfl_xor(xacc, 1);
  xacc += __shfl_xor(xacc, 2);
  xacc += __shfl_xor(xacc, 4);
  if (ag == 0) lxsq[ar] = xacc;
  __syncthreads();

  // ---- epilogue: q = rcp(1 + xsq + csq - 2*dot); fused row-normalize ----
  float cs[8];
  #pragma unroll
  for (int ni = 0; ni < 8; ++ni)
    cs[ni] = csq[w * 128 + ni * 16 + p];   // tiny, L2-hot

  float rp[2][4];
  #pragma unroll
  for (int mi = 0; mi < 2; ++mi)
    #pragma unroll
    for (int rr = 0; rr < 4; ++rr)
      rp[mi][rr] = 0.f;

  #pragma unroll
  for (int mi = 0; mi < 2; ++mi) {
    #pragma unroll
    for (int rr = 0; rr < 4; ++rr) {
      const float xsv = lxsq[mi * 16 + quad * 4 + rr];
      #pragma unroll
      for (int ni = 0; ni < 8; ++ni) {
        const float d = 1.0f + xsv + cs[ni] - 2.0f * acc[mi][ni][rr];
        const float q = __builtin_amdgcn_rcpf(d);  // d ~ 1000, 1ulp is plenty
        acc[mi][ni][rr] = q;
        rp[mi][rr] += q;
      }
    }
  }

  #pragma unroll
  for (int mi = 0; mi < 2; ++mi)
    #pragma unroll
    for (int rr = 0; rr < 4; ++rr) {
      float v = rp[mi][rr];
      v += __shfl_xor(v, 1);
      v += __shfl_xor(v, 2);
      v += __shfl_xor(v, 4);
      v += __shfl_xor(v, 8);
      if (p == 0) atomicAdd(&lrow[mi * 16 + quad * 4 + rr], v);
    }
  __syncthreads();

  // direct non-temporal stores: 16 lanes x 4B = 64B contiguous per quad-row
  #pragma unroll
  for (int mi = 0; mi < 2; ++mi) {
    #pragma unroll
    for (int rr = 0; rr < 4; ++rr) {
      const int row = mi * 16 + quad * 4 + rr;
      const float inv = __builtin_amdgcn_rcpf(lrow[row]);
      float* orow = out + (size_t)(row0 + row) * K + w * 128 + p;
      #pragma unroll
      for (int ni = 0; ni < 8; ++ni)
        __builtin_nontemporal_store(acc[mi][ni][rr] * inv, orow + ni * 16);
    }
  }
}

extern "C" void kernel_launch(void* const* d_in, const int* in_sizes, int n_in,
                              void* d_out, int out_size, void* d_ws, size_t ws_size,
                              hipStream_t stream) {
  const float* x    = (const float*)d_in[0];
  const float* cent = (const float*)d_in[1];
  float* out = (float*)d_out;

  // ws layout: csq[512] floats (2KB) | bbf bf16 image (512KB). Needs 526KB.
  float*    csq = (float*)d_ws;
  uint16_t* bbf = (uint16_t*)((char*)d_ws + 2048);

  const int N = in_sizes[0] / D;      // 65536
  prep_kernel<<<K, 64, 0, stream>>>(cent, csq, bbf);
  cluster_main<<<N / BM, THREADS, 0, stream>>>(x, bbf, csq, out);
}